// Round 7
// baseline (56.210 us; speedup 1.0000x reference)
//
#include <hip/hip_runtime.h>

// EdgeConv2d: B=4, C=64, N=8192, K=16, C_OUT=64
// out[b,o,n] = relu( max_k ( y1[b, i1(b,n,k), o] + y2[b, i0(b,n,k), o] ) + bias[o] )
// y1 = (W[:,:C] - W[:,C:]) @ x[b],  y2 = W[:,C:] @ x[b]
// y (fp16): y[b][n][s], s<64 -> y1[s], s>=64 -> y2[s-64]. Row = 256 B.
// Gather v3: dwordx4 per lane (16 B = 8 chans) -> 4x fewer divergent lane-
// addresses than dword loads. Wave = chan-slice, lane = node, k-max in-lane.

#define BB   4
#define CCH  64
#define NN   8192
#define KK   16

typedef _Float16 h4 __attribute__((ext_vector_type(4)));
typedef _Float16 h8 __attribute__((ext_vector_type(8)));
typedef int      v4i __attribute__((ext_vector_type(4)));
typedef float    v4f __attribute__((ext_vector_type(4)));

// ---------------------------------------------------------------------------
// Kernel 1: y GEMM (fp32 accumulate, fp16 store). Unchanged from round 4.
// ---------------------------------------------------------------------------
__global__ __launch_bounds__(256) void gemm_kernel(const float* __restrict__ x,
                                                   const float* __restrict__ W,
                                                   _Float16* __restrict__ y) {
    __shared__ float wT[64 * 132];
    __shared__ float xs[64 * 64];

    const int t   = threadIdx.x;
    const int blk = blockIdx.x;               // 512 blocks
    const int xcd  = blk & 7;
    const int b    = xcd >> 1;
    const int tile = ((blk >> 3) << 1) | (xcd & 1);   // 0..127
    const int n0   = tile * 64;

    {
        const int sbase = t >> 6;
        const int k     = t & 63;
        #pragma unroll
        for (int i = 0; i < 32; ++i) {
            const int s = sbase + (i << 2);
            float v;
            if (s < CCH) v = W[s * 128 + k] - W[s * 128 + 64 + k];
            else         v = W[(s - CCH) * 128 + 64 + k];
            wT[k * 132 + s] = v;
        }
    }
    {
        const float* xb = x + (size_t)b * CCH * NN + n0;
        #pragma unroll
        for (int i = 0; i < 16; ++i) {
            const int e = t + (i << 8);
            const int k = e >> 6, n = e & 63;
            xs[k * 64 + n] = xb[(size_t)k * NN + n];
        }
    }
    __syncthreads();

    const int c_grp = t & 31;
    const int n_grp = t >> 5;

    float acc[4][8];
    #pragma unroll
    for (int i = 0; i < 4; ++i)
        #pragma unroll
        for (int j = 0; j < 8; ++j) acc[i][j] = 0.f;

    #pragma unroll 8
    for (int k = 0; k < 64; ++k) {
        const float4 wv  = *(const float4*)&wT[k * 132 + 4 * c_grp];
        const float4 xv0 = *(const float4*)&xs[k * 64 + 8 * n_grp];
        const float4 xv1 = *(const float4*)&xs[k * 64 + 8 * n_grp + 4];
        const float wa[4] = {wv.x, wv.y, wv.z, wv.w};
        const float xa[8] = {xv0.x, xv0.y, xv0.z, xv0.w, xv1.x, xv1.y, xv1.z, xv1.w};
        #pragma unroll
        for (int i = 0; i < 4; ++i)
            #pragma unroll
            for (int j = 0; j < 8; ++j)
                acc[i][j] += wa[i] * xa[j];
    }

    _Float16* ybp = y + ((size_t)b * NN + n0) * 128 + 4 * c_grp;
    #pragma unroll
    for (int j = 0; j < 8; ++j) {
        h4 v;
        v.x = (_Float16)acc[0][j]; v.y = (_Float16)acc[1][j];
        v.z = (_Float16)acc[2][j]; v.w = (_Float16)acc[3][j];
        *(h4*)&ybp[(size_t)(8 * n_grp + j) * 128] = v;
    }
}

// ---------------------------------------------------------------------------
// Kernel 2: gather v3. 512 blocks x 512 threads; block = (b, 64-node tile).
// Wave w = chans 8w..8w+7; lane = node. Per (node,k): two dwordx4 loads
// (y1-slice, y2-slice), pk_add + pk_max in-lane. Edge rows staged in LDS once.
// ---------------------------------------------------------------------------
__global__ __launch_bounds__(512) void gather_kernel(const _Float16* __restrict__ y,
                                                     const int* __restrict__ edge,
                                                     const float* __restrict__ bias,
                                                     float* __restrict__ out) {
    __shared__ int   eL[64][2][17];   // [node][src][k], pad 17: 2-way banks (free)
    __shared__ float sm[64][66];      // [node][chan]

    const int t   = threadIdx.x;      // 0..511
    const int blk = blockIdx.x;       // 512 = b(4) x tile(128)
    const int b   = blk >> 7;
    const int n0  = (blk & 127) * 64;

    // Stage edge rows: t -> (src = t>>8, node = (t>>2)&63, k-quad = t&3).
    {
        const int src = t >> 8;                // 0 -> e1 (centers, y1), 1 -> e0 (-> y2)
        const int n   = (t >> 2) & 63;
        const int kq  = (t & 3) * 4;
        const size_t ebase = (size_t)(src == 0 ? BB + b : b) * NN * KK;
        *(v4i*)&eL[n][src][kq] = *(const v4i*)&edge[ebase + (size_t)(n0 + n) * KK + kq];
    }
    __syncthreads();

    const int w    = t >> 6;          // chan slice: chans 8w..8w+7
    const int lane = t & 63;          // node
    const int co   = w * 8;
    const _Float16* yb = y + (size_t)b * NN * 128;

    h8 m;
    #pragma unroll 4
    for (int k = 0; k < 16; ++k) {
        const int i1 = eL[lane][0][k];
        const int i0 = eL[lane][1][k];
        const h8 a = *(const h8*)&yb[(size_t)i1 * 128 + co];        // y1 slice
        const h8 c = *(const h8*)&yb[(size_t)i0 * 128 + 64 + co];   // y2 slice
        const h8 s = a + c;                      // 4x v_pk_add_f16
        m = (k == 0) ? s : __builtin_elementwise_max(m, s);   // 4x v_pk_max_f16
    }

    // bias + relu -> sm[node][chan]
    {
        const v4f b0 = *(const v4f*)&bias[co];       // wave-uniform -> s_load
        const v4f b1 = *(const v4f*)&bias[co + 4];
        float r[8];
        r[0] = fmaxf((float)m[0] + b0.x, 0.f);
        r[1] = fmaxf((float)m[1] + b0.y, 0.f);
        r[2] = fmaxf((float)m[2] + b0.z, 0.f);
        r[3] = fmaxf((float)m[3] + b0.w, 0.f);
        r[4] = fmaxf((float)m[4] + b1.x, 0.f);
        r[5] = fmaxf((float)m[5] + b1.y, 0.f);
        r[6] = fmaxf((float)m[6] + b1.z, 0.f);
        r[7] = fmaxf((float)m[7] + b1.w, 0.f);
        #pragma unroll
        for (int j = 0; j < 4; ++j)
            *(float2*)&sm[lane][co + 2 * j] = make_float2(r[2 * j], r[2 * j + 1]);
    }
    __syncthreads();

    // Transposed coalesced stores: 1024 (c, n-quad) pairs, 2 per thread.
    #pragma unroll
    for (int r2 = 0; r2 < 2; ++r2) {
        const int idx = t + (r2 << 9);    // 0..1023
        const int c   = idx >> 4;         // 0..63
        const int q   = idx & 15;         // 0..15
        v4f v;
        v.x = sm[4 * q + 0][c];
        v.y = sm[4 * q + 1][c];
        v.z = sm[4 * q + 2][c];
        v.w = sm[4 * q + 3][c];
        *(v4f*)(out + ((size_t)b * CCH + c) * NN + n0 + 4 * q) = v;
    }
}

extern "C" void kernel_launch(void* const* d_in, const int* in_sizes, int n_in,
                              void* d_out, int out_size, void* d_ws, size_t ws_size,
                              hipStream_t stream) {
    (void)in_sizes; (void)n_in; (void)out_size; (void)ws_size;
    const float* x    = (const float*)d_in[0];
    const int*   edge = (const int*)d_in[1];
    const float* W    = (const float*)d_in[2];
    const float* bias = (const float*)d_in[3];
    float*       out  = (float*)d_out;
    _Float16*    y    = (_Float16*)d_ws;    // [B][N][128] fp16 = 8 MB

    gemm_kernel<<<dim3(512), dim3(256), 0, stream>>>(x, W, y);
    gather_kernel<<<dim3(512), dim3(512), 0, stream>>>(y, edge, bias, out);
}

// Round 8
// 27.200 us; speedup vs baseline: 2.0665x; 2.0665x over previous
//
#include <hip/hip_runtime.h>

// EdgeConv2d: B=4, C=64, N=8192, K=16, C_OUT=64
// out[b,o,n] = relu( max_k ( y1[b, i1(b,n,k), o] + y2[b, i0(b,n,k), o] ) + bias[o] )
// y1 = (W[:,:C] - W[:,C:]) @ x[b],  y2 = W[:,C:] @ x[b]
// y (fp16): y[b][n][s], s<64 -> y1[s], s>=64 -> y2[s-64]. Row = 256 B.
// GEMM v2: fp16 LDS operands, k-pair interleaved, v_dot2_f32_f16 inner loop.
// Gather: EXACT round-4 structure (at the ~11cyc/CU line-fill floor).

#define BB   4
#define CCH  64
#define NN   8192
#define KK   16

typedef _Float16 h2  __attribute__((ext_vector_type(2)));
typedef _Float16 h8  __attribute__((ext_vector_type(8)));
typedef _Float16 h16 __attribute__((ext_vector_type(16)));
typedef int      v4i __attribute__((ext_vector_type(4)));

#if __has_builtin(__builtin_amdgcn_fdot2)
#define FDOT2(a, b, c) __builtin_amdgcn_fdot2((a), (b), (c), false)
#else
#define FDOT2(a, b, c) ((c) + (float)(a).x * (float)(b).x + (float)(a).y * (float)(b).y)
#endif

// ---------------------------------------------------------------------------
// Kernel 1: y GEMM. 256 blocks (b x 64 n-tiles of 128), 256 thr, thread=8s x 8n.
// LDS rows hold k-pair-interleaved fp16: [kp][2*col + (k&1)], row = 264 fp16.
// ---------------------------------------------------------------------------
__global__ __launch_bounds__(256) void gemm_kernel(const float* __restrict__ x,
                                                   const float* __restrict__ W,
                                                   _Float16* __restrict__ y) {
    __shared__ _Float16 wT2[32 * 264];   // [kp][2s+p], s = 0..127 stacked chans
    __shared__ _Float16 xs2[32 * 264];   // [kp][2n+p], n = 0..127

    const int t   = threadIdx.x;
    const int blk = blockIdx.x;           // 256 = b(4) x ntile(64)
    const int b   = blk >> 6;
    const int n0  = (blk & 63) * 128;

    // Stage W' (s<64: W1-W2, s>=64: W2), coalesced over k.
    {
        const int k  = t & 63;
        const int kp = k >> 1, par = k & 1;
        const int sb = t >> 6;
        #pragma unroll
        for (int i = 0; i < 32; ++i) {
            const int s = sb + 4 * i;
            float v;
            if (s < CCH) v = W[s * 128 + k] - W[s * 128 + 64 + k];
            else         v = W[(s - CCH) * 128 + 64 + k];
            wT2[kp * 264 + 2 * s + par] = (_Float16)v;
        }
    }
    // Stage x tile [64 k][128 n], float4 coalesced reads.
    {
        const float* xb = x + (size_t)b * CCH * NN + n0;
        #pragma unroll
        for (int i = 0; i < 8; ++i) {
            const int k  = (t >> 5) + 8 * i;
            const int nq = (t & 31) * 4;
            const float4 v = *(const float4*)&xb[(size_t)k * NN + nq];
            const int kp = k >> 1, par = k & 1;
            _Float16* d = &xs2[kp * 264 + 2 * nq + par];
            d[0] = (_Float16)v.x; d[2] = (_Float16)v.y;
            d[4] = (_Float16)v.z; d[6] = (_Float16)v.w;
        }
    }
    __syncthreads();

    const int sg = t & 15;    // s0 = 8*sg
    const int ng = t >> 4;    // n  = 8*ng ..
    const int s0 = sg * 8, nn0 = ng * 8;

    float acc[8][8];
    #pragma unroll
    for (int i = 0; i < 8; ++i)
        #pragma unroll
        for (int j = 0; j < 8; ++j) acc[i][j] = 0.f;

    #pragma unroll 2
    for (int kp = 0; kp < 32; ++kp) {
        const h16 wv = *(const h16*)&wT2[kp * 264 + 2 * s0];
        const h16 xv = *(const h16*)&xs2[kp * 264 + 2 * nn0];
        #pragma unroll
        for (int i = 0; i < 8; ++i) {
            h2 wp; wp.x = wv[2 * i]; wp.y = wv[2 * i + 1];
            #pragma unroll
            for (int j = 0; j < 8; ++j) {
                h2 xp; xp.x = xv[2 * j]; xp.y = xv[2 * j + 1];
                acc[i][j] = FDOT2(wp, xp, acc[i][j]);
            }
        }
    }

    // Store: y[(b*N + n)*128 + s0..s0+7] fp16, 16 B/lane, coalesced per wave.
    _Float16* yb = y + ((size_t)b * NN + n0 + nn0) * 128 + s0;
    #pragma unroll
    for (int j = 0; j < 8; ++j) {
        h8 v;
        #pragma unroll
        for (int i = 0; i < 8; ++i) v[i] = (_Float16)acc[i][j];
        *(h8*)&yb[(size_t)j * 128] = v;
    }
}

// ---------------------------------------------------------------------------
// Kernel 2: gather (EXACT round-4 structure). 2048 blocks x 256 thr.
// Half-wave = one (node, k); 32 lanes x 4 B inside one 128 B line -> 2 lines
// per instruction, the measured line-fill floor.
// ---------------------------------------------------------------------------
__global__ __launch_bounds__(256) void gather_kernel(const _Float16* __restrict__ y,
                                                     const int* __restrict__ edge,
                                                     const float* __restrict__ bias,
                                                     float* __restrict__ out) {
    __shared__ int   eL[16][2][16];   // [nl][src][k] src0=e1(center->y1), src1=e0(->y2)
    __shared__ float so[16][65];

    const int t   = threadIdx.x;
    const int blk = blockIdx.x;       // 2048
    const int xcd  = blk & 7;
    const int b    = xcd >> 1;
    const int tile = ((blk >> 3) << 1) | (xcd & 1);   // 0..511
    const int n0   = tile * 16;

    if (t < 128) {
        const int src = t >> 6;                 // 0 -> e1, 1 -> e0
        const int f   = (t & 63) << 2;
        const int nl  = f >> 4, k0 = f & 15;
        const size_t eb = (size_t)(src == 0 ? BB + b : b) * NN * KK;
        *(v4i*)&eL[nl][src][k0] = *(const v4i*)&edge[eb + (size_t)(n0 + nl) * KK + k0];
    }
    __syncthreads();

    const int w    = t >> 6;
    const int lane = t & 63;
    const int half = lane >> 5;       // which k of each pair
    const int cl   = lane & 31;       // channel pair: {2cl, 2cl+1}

    const float2 bv = *(const float2*)&bias[2 * cl];
    const _Float16* yb = y + (size_t)b * NN * 128;

    #pragma unroll 2
    for (int u = 0; u < 4; ++u) {
        const int nl = 4 * w + u;
        h2 s[8];
        #pragma unroll
        for (int kp = 0; kp < 8; ++kp) {
            const int k  = 2 * kp + half;
            const int i1 = eL[nl][0][k];
            const int i0 = eL[nl][1][k];
            const uint a = *(const uint*)&yb[(size_t)i1 * 128 + 2 * cl];       // y1
            const uint c = *(const uint*)&yb[(size_t)i0 * 128 + 64 + 2 * cl];  // y2
            union { uint u32; h2 h; } ua, uc;
            ua.u32 = a; uc.u32 = c;
            s[kp] = ua.h + uc.h;                // v_pk_add_f16
        }
        h2 m = s[0];
        #pragma unroll
        for (int kp = 1; kp < 8; ++kp) m = __builtin_elementwise_max(m, s[kp]);
        union { int i32; h2 h; } um, uo;
        um.h = m;
        uo.i32 = __shfl_xor(um.i32, 32, 64);
        m = __builtin_elementwise_max(m, uo.h);
        if (half == 0) {
            float2 r;
            r.x = fmaxf((float)m.x + bv.x, 0.f);
            r.y = fmaxf((float)m.y + bv.y, 0.f);
            *(float2*)&so[nl][2 * cl] = r;
        }
    }
    __syncthreads();

    {
        const int c = t >> 2;
        const int q = t & 3;
        float4 v;
        v.x = so[4 * q + 0][c];
        v.y = so[4 * q + 1][c];
        v.z = so[4 * q + 2][c];
        v.w = so[4 * q + 3][c];
        *(float4*)(out + ((size_t)b * CCH + c) * NN + n0 + 4 * q) = v;
    }
}

extern "C" void kernel_launch(void* const* d_in, const int* in_sizes, int n_in,
                              void* d_out, int out_size, void* d_ws, size_t ws_size,
                              hipStream_t stream) {
    (void)in_sizes; (void)n_in; (void)out_size; (void)ws_size;
    const float* x    = (const float*)d_in[0];
    const int*   edge = (const int*)d_in[1];
    const float* W    = (const float*)d_in[2];
    const float* bias = (const float*)d_in[3];
    float*       out  = (float*)d_out;
    _Float16*    y    = (_Float16*)d_ws;    // [B][N][128] fp16 = 8 MB

    gemm_kernel<<<dim3(256), dim3(256), 0, stream>>>(x, W, y);
    gather_kernel<<<dim3(2048), dim3(256), 0, stream>>>(y, edge, bias, out);
}